// Round 3
// baseline (1515.057 us; speedup 1.0000x reference)
//
#include <hip/hip_runtime.h>

#define N_NODES 500000
#define N_EDGES 8000000
#define N_GRAPHS 8192
#define POOL_CH 128
#define SCAN_B 256
#define SCAN_E 4
#define SCAN_TILE 1024   // SCAN_B * SCAN_E

// ---------------- utility ----------------
__global__ void k_fill(float* __restrict__ p, float v, int n) {
    int i = blockIdx.x * 256 + threadIdx.x;
    if (i < n) p[i] = v;
}
__global__ void k_filli(int* __restrict__ p, int v, int n) {
    int i = blockIdx.x * 256 + threadIdx.x;
    if (i < n) p[i] = v;
}

// in-degree histogram (int)
__global__ void k_hist(const int* __restrict__ col, int* __restrict__ degc, int E) {
    int e = blockIdx.x * 256 + threadIdx.x;
    if (e < E) {
        unsigned c = (unsigned)col[e];
        if (c < N_NODES) atomicAdd(&degc[c], 1);
    }
}

// dinv = rsqrt(1 + in_degree)   (the +1 is the self-loop)
__global__ void k_dinv(const int* __restrict__ degc, float* __restrict__ dinv, int n) {
    int i = blockIdx.x * 256 + threadIdx.x;
    if (i < n) dinv[i] = rsqrtf(1.0f + (float)degc[i]);
}

// ---- hierarchical exclusive scan of degc -> rowptr ----
__global__ void k_scan_reduce(const int* __restrict__ in, int* __restrict__ bsum, int n) {
    __shared__ int sd[SCAN_B];
    int t = threadIdx.x;
    int base = blockIdx.x * SCAN_TILE + t * SCAN_E;
    int s = 0;
#pragma unroll
    for (int k = 0; k < SCAN_E; k++) { int i = base + k; if (i < n) s += in[i]; }
    sd[t] = s; __syncthreads();
    for (int d = SCAN_B / 2; d > 0; d >>= 1) {
        if (t < d) sd[t] += sd[t + d];
        __syncthreads();
    }
    if (t == 0) bsum[blockIdx.x] = sd[0];
}

__global__ void k_scan_bsum(int* __restrict__ bsum, int nb) {
    __shared__ int sd[512];
    int t = threadIdx.x;
    int v = (t < nb) ? bsum[t] : 0;
    sd[t] = v; __syncthreads();
    for (int d = 1; d < 512; d <<= 1) {
        int tv = (t >= d) ? sd[t - d] : 0;
        __syncthreads();
        sd[t] += tv;
        __syncthreads();
    }
    if (t < nb) bsum[t] = sd[t] - v;   // exclusive
}

__global__ void k_scan_write(const int* __restrict__ in, const int* __restrict__ bsum,
                             int* __restrict__ rowptr, int n) {
    __shared__ int sd[SCAN_B];
    int t = threadIdx.x;
    int base = blockIdx.x * SCAN_TILE + t * SCAN_E;
    int v[SCAN_E]; int s = 0;
#pragma unroll
    for (int k = 0; k < SCAN_E; k++) { int i = base + k; v[k] = (i < n) ? in[i] : 0; s += v[k]; }
    sd[t] = s; __syncthreads();
    for (int d = 1; d < SCAN_B; d <<= 1) {
        int tv = (t >= d) ? sd[t - d] : 0;
        __syncthreads();
        sd[t] += tv;
        __syncthreads();
    }
    int run = sd[t] - s + bsum[blockIdx.x];
#pragma unroll
    for (int k = 0; k < SCAN_E; k++) {
        int i = base + k;
        if (i < n) {
            rowptr[i] = run;
            run += v[k];
            if (i == n - 1) rowptr[n] = run;
        }
    }
}

// permute: srcids grouped by target, cursor pre-initialized to rowptr copy
__global__ void k_fillidx(const int* __restrict__ row, const int* __restrict__ col,
                          int* __restrict__ cursor, int* __restrict__ srcids, int E) {
    int e = blockIdx.x * 256 + threadIdx.x;
    if (e < E) {
        unsigned c = (unsigned)col[e];
        unsigned r = (unsigned)row[e];
        if (c < N_NODES && r < N_NODES) {
            int pos = atomicAdd(&cursor[c], 1);
            srcids[pos] = (int)r;
        }
    }
}

// layer-1 node transform: hs = (x @ W1) * dinv
__global__ void k_l1(const float* __restrict__ x, const float* __restrict__ W1,
                     const float* __restrict__ dinv, float* __restrict__ hs, int n) {
    int v = blockIdx.x * 256 + threadIdx.x;
    if (v >= n) return;
    float xi[9];
#pragma unroll
    for (int k = 0; k < 9; k++) xi[k] = x[v * 9 + k];
    float di = dinv[v];
#pragma unroll
    for (int j = 0; j < 16; j++) {
        float acc = 0.f;
#pragma unroll
        for (int k = 0; k < 9; k++) acc += xi[k] * W1[k * 16 + j];
        hs[v * 16 + j] = acc * di;
    }
}

// pull aggregation: out[v] = hs[v] (self loop) + sum_{r in in(v)} hs[r]
// 16 lanes per node, one feature each: gathers are exactly one 64B line/edge
__global__ void k_pull(const int* __restrict__ rowptr, const int* __restrict__ srcids,
                       const float* __restrict__ hs, float* __restrict__ out, int n) {
    int tid = blockIdx.x * 256 + threadIdx.x;
    int v = tid >> 4;
    int j = tid & 15;
    if (v >= n) return;
    int s = rowptr[v], e = rowptr[v + 1];
    float acc = hs[v * 16 + j];   // self loop (hs already scaled by dinv)
    for (int k = s; k < e; k++) {
        int r = srcids[k];
        acc += hs[r * 16 + j];
    }
    out[v * 16 + j] = acc;
}

// layer-2 node transform: h1 = relu(agg*dinv + b1); hs2 = (h1 @ W2)*dinv
__global__ void k_l2(const float* __restrict__ W2, const float* __restrict__ b1,
                     const float* __restrict__ dinv, const float* __restrict__ agg,
                     float* __restrict__ hs, int n) {
    int v = blockIdx.x * 256 + threadIdx.x;
    if (v >= n) return;
    float di = dinv[v];
    float h1[16];
#pragma unroll
    for (int j = 0; j < 16; j++) {
        float t = agg[v * 16 + j] * di + b1[j];
        h1[j] = t > 0.f ? t : 0.f;
    }
#pragma unroll
    for (int j = 0; j < 16; j++) {
        float acc = 0.f;
#pragma unroll
        for (int k = 0; k < 16; k++) acc += h1[k] * W2[k * 16 + j];
        hs[v * 16 + j] = acc * di;
    }
}

// pool exploiting sorted batch: register accumulate, flush per graph boundary
__global__ void k_pool2(const float* __restrict__ agg, const float* __restrict__ dinv,
                        const float* __restrict__ b2, const int* __restrict__ batch,
                        float* __restrict__ pooled, float* __restrict__ cnt, int n) {
    int tid = blockIdx.x * 256 + threadIdx.x;
    int chunk = tid >> 4;
    int j = tid & 15;
    int start = chunk * POOL_CH;
    if (start >= n) return;
    int end = start + POOL_CH;
    if (end > n) end = n;
    float bj = b2[j];
    int g_cur = batch[start];
    float acc = 0.f;
    float c_acc = 0.f;
    for (int v = start; v < end; v++) {
        int g = batch[v];
        if (g != g_cur) {
            atomicAdd(&pooled[g_cur * 16 + j], acc);
            if (j == 0) atomicAdd(&cnt[g_cur], c_acc);
            acc = 0.f; c_acc = 0.f; g_cur = g;
        }
        float t = agg[v * 16 + j] * dinv[v] + bj;
        acc += t > 0.f ? t : 0.f;
        c_acc += 1.f;
    }
    atomicAdd(&pooled[g_cur * 16 + j], acc);
    if (j == 0) atomicAdd(&cnt[g_cur], c_acc);
}

// head MLP
__global__ void k_head(const float* __restrict__ pooled, const float* __restrict__ cnt,
                       const float* __restrict__ meta, const float* __restrict__ Wh1,
                       const float* __restrict__ bh1, const float* __restrict__ Wh2,
                       const float* __restrict__ bh2, float* __restrict__ out, int G) {
    int g = blockIdx.x * 256 + threadIdx.x;
    if (g >= G) return;
    float z[43];
    float c = cnt[g];
    c = c > 1.f ? c : 1.f;
#pragma unroll
    for (int j = 0; j < 16; j++) z[j] = pooled[g * 16 + j] / c;
#pragma unroll
    for (int j = 0; j < 27; j++) z[16 + j] = meta[g * 27 + j];
    float acc2 = bh2[0];
#pragma unroll
    for (int jj = 0; jj < 16; jj++) {
        float a = bh1[jj];
#pragma unroll
        for (int k = 0; k < 43; k++) a += z[k] * Wh1[k * 16 + jj];
        a = a > 0.f ? a : 0.f;
        acc2 += a * Wh2[jj];
    }
    out[g] = acc2;
}

extern "C" void kernel_launch(void* const* d_in, const int* in_sizes, int n_in,
                              void* d_out, int out_size, void* d_ws, size_t ws_size,
                              hipStream_t stream) {
    const float* x    = (const float*)d_in[0];
    const int*   ei   = (const int*)d_in[1];   // [2, E]: row then col
    const int*   batch= (const int*)d_in[2];
    const float* meta = (const float*)d_in[3];
    const float* W1   = (const float*)d_in[4];
    const float* b1   = (const float*)d_in[5];
    const float* W2   = (const float*)d_in[6];
    const float* b2   = (const float*)d_in[7];
    const float* Wh1  = (const float*)d_in[8];
    const float* bh1  = (const float*)d_in[9];
    const float* Wh2  = (const float*)d_in[10];
    const float* bh2  = (const float*)d_in[11];
    float* out = (float*)d_out;

    const int N = N_NODES, E = N_EDGES, G = N_GRAPHS;
    const int* row = ei;
    const int* col = ei + E;

    // workspace layout (4-byte units)
    float* ws     = (float*)d_ws;
    float* dinv   = ws;                       // N
    float* hs     = ws + 512000;              // N*16
    float* agg    = hs + 8000000;             // N*16
    float* pooled = agg + 8000000;            // G*16
    float* cnt    = pooled + G * 16;          // G
    int*   rowptr = (int*)(cnt + G);          // N+1
    int*   degc   = rowptr + 512000;          // N (later reused as cursor)
    int*   bsum   = degc + 512000;            // 512
    int*   srcids = bsum + 512;               // E

    dim3 blk(256);
    int gN = (N + 255) / 256;
    int gE = (E + 255) / 256;
    int nblk = (N + SCAN_TILE - 1) / SCAN_TILE;   // 489

    // ---- CSR build ----
    k_filli<<<gN, blk, 0, stream>>>(degc, 0, N);
    k_fill<<<(G * 17 + 255) / 256, blk, 0, stream>>>(pooled, 0.0f, G * 17);
    k_hist<<<gE, blk, 0, stream>>>(col, degc, E);
    k_dinv<<<gN, blk, 0, stream>>>(degc, dinv, N);
    k_scan_reduce<<<nblk, blk, 0, stream>>>(degc, bsum, N);
    k_scan_bsum<<<1, 512, 0, stream>>>(bsum, nblk);
    k_scan_write<<<nblk, blk, 0, stream>>>(degc, bsum, rowptr, N);
    // cursor := rowptr  (degc reused as cursor)
    hipMemcpyAsync(degc, rowptr, (size_t)N * sizeof(int), hipMemcpyDeviceToDevice, stream);
    k_fillidx<<<gE, blk, 0, stream>>>(row, col, degc, srcids, E);

    // ---- layer 1 ----
    k_l1<<<gN, blk, 0, stream>>>(x, W1, dinv, hs, N);
    int gP16 = (N * 16 + 255) / 256;
    k_pull<<<gP16, blk, 0, stream>>>(rowptr, srcids, hs, agg, N);

    // ---- layer 2 ----
    k_l2<<<gN, blk, 0, stream>>>(W2, b1, dinv, agg, hs, N);
    k_pull<<<gP16, blk, 0, stream>>>(rowptr, srcids, hs, agg, N);

    // ---- pool + head ----
    int chunks = (N + POOL_CH - 1) / POOL_CH;
    int gPool = (chunks * 16 + 255) / 256;
    k_pool2<<<gPool, blk, 0, stream>>>(agg, dinv, b2, batch, pooled, cnt, N);
    k_head<<<(G + 255) / 256, blk, 0, stream>>>(pooled, cnt, meta, Wh1, bh1, Wh2, bh2, out, G);
}